// Round 5
// baseline (315.520 us; speedup 1.0000x reference)
//
#include <hip/hip_runtime.h>

typedef __attribute__((ext_vector_type(8))) short short8;
typedef __attribute__((ext_vector_type(4))) float f32x4;

__device__ __forceinline__ unsigned short f2bf(float f) {
  unsigned u = __float_as_uint(f);
  u += 0x7FFF + ((u >> 16) & 1);
  return (unsigned short)(u >> 16);
}
__device__ __forceinline__ float bf2f(unsigned short h) {
  return __uint_as_float(((unsigned)h) << 16);
}

// ---------------- kernel 1: h2 row-sums (hbar accumulation) ----------------
// grid 8 x 256 (proven: ~5.6 us, LDS work spread over 8 CUs).
__global__ __launch_bounds__(256) void mlp_h2_kernel(
    const float* __restrict__ w1, const float* __restrict__ b1,
    const float* __restrict__ w2, const float* __restrict__ b2,
    float* __restrict__ hbar)
{
  __shared__ float W2T[64][65];
  __shared__ float h1s[32][64];
  __shared__ float partial[4][64];
  const int t = threadIdx.x;
  const int k = t & 63, rg = t >> 6;

  for (int v = 0; v < 16; ++v) {
    int idx = v * 256 + t;
    W2T[idx & 63][idx >> 6] = w2[idx];
  }
  const int r0 = blockIdx.x * 32;
  for (int v = 0; v < 8; ++v) {
    int idx = v * 256 + t;
    int rl = idx >> 6, j = idx & 63;
    int r = r0 + rl;
    float gx = (float)(r >> 4) * (1.0f / 15.0f);
    float gy = (float)(r & 15) * (1.0f / 15.0f);
    float h = gx * w1[2 * j] + gy * w1[2 * j + 1] + b1[j];
    h1s[rl][j] = fmaxf(h, 0.0f);
  }
  __syncthreads();

  float acc[8] = {0, 0, 0, 0, 0, 0, 0, 0};
  for (int j = 0; j < 64; ++j) {
    float w = W2T[j][k];
#pragma unroll
    for (int rr = 0; rr < 8; ++rr)
      acc[rr] += h1s[rg * 8 + rr][j] * w;
  }
  float b2v = b2[k];
  float s = 0.0f;
#pragma unroll
  for (int rr = 0; rr < 8; ++rr) s += fmaxf(acc[rr] + b2v, 0.0f);
  partial[rg][k] = s;
  __syncthreads();
  if (t < 64) {
    atomicAdd(&hbar[t], partial[0][t] + partial[1][t] + partial[2][t] + partial[3][t]);
  }
}

// ---------------- kernel 2: Mf (inline) + build fused per-channel operator T ----
__global__ __launch_bounds__(1024) void build_TM_kernel(
    const float* __restrict__ hbar, const float* __restrict__ w3,
    const float* __restrict__ b3, unsigned short* __restrict__ wsT,
    float* __restrict__ outMf)
{
  __shared__ float Dl[16][16];
  __shared__ float Ml[256];
  __shared__ float Gl[16][16][16];
  const int t = threadIdx.x;
  const int c = blockIdx.x >> 1;
  const int bh = blockIdx.x & 1;

  if (t < 256) {
    int i = t >> 4, k = t & 15;
    float sc = (i == 0) ? 0.25f : 0.35355339059327373f;
    Dl[i][k] = sc * cosf(3.14159265358979323846f * (float)((2 * i + 1) * k) * (1.0f / 32.0f));
    int j = c * 256 + t;
    float s = 0.f;
    for (int kk = 0; kk < 64; ++kk) s += hbar[kk] * w3[j * 64 + kk];
    float o = b3[j] + s * (1.0f / 256.0f);
    float m = 1.0f / (1.0f + expf(-o));
    Ml[t] = m;
    if (bh == 0) outMf[j] = m;
  }
  __syncthreads();

  for (int e = t; e < 4096; e += 1024) {
    int i = e >> 8, ss = (e >> 4) & 15, v = e & 15;
    float g = 0.f;
#pragma unroll
    for (int l = 0; l < 16; ++l)
      g += Ml[i * 16 + l] * Dl[l][ss] * Dl[l][v];
    Gl[i][ss][v] = g;
  }
  __syncthreads();

  const int oc = bh * 128 + (t >> 3);
  const int jsel = t & 7;
  const int r = oc >> 4, ss = oc & 15;
  const int j0 = jsel * 2, j1 = j0 + 1;
  float a0[16], a1[16];
#pragma unroll
  for (int k = 0; k < 16; ++k) { a0[k] = 0.f; a1[k] = 0.f; }
  for (int i = 0; i < 16; ++i) {
    float wr = Dl[i][r];
    float G16[16];
    const float* gp = &Gl[i][ss][0];
#pragma unroll
    for (int k = 0; k < 16; ++k) G16[k] = gp[k];
    float w0 = wr * Dl[i][j0];
    float w1v = wr * Dl[i][j1];
#pragma unroll
    for (int k = 0; k < 16; ++k) { a0[k] += w0 * G16[k]; a1[k] += w1v * G16[k]; }
  }
  unsigned short* dst = wsT + (size_t)c * 65536 + (size_t)oc * 256;
  unsigned* d0 = (unsigned*)(dst + j0 * 16);
  unsigned* d1 = (unsigned*)(dst + j1 * 16);
#pragma unroll
  for (int k = 0; k < 8; ++k)
    d0[k] = (unsigned)f2bf(a0[2 * k]) | ((unsigned)f2bf(a0[2 * k + 1]) << 16);
#pragma unroll
  for (int k = 0; k < 8; ++k)
    d1[k] = (unsigned)f2bf(a1[2 * k]) | ((unsigned)f2bf(a1[2 * k + 1]) << 16);
}

// ---------------- main kernel: streaming GEMM, counted-vmcnt single-barrier pipe --
// grid 510 x 512. A triple-buffered (3x8 KB bf16) + R double-buffered (2x16 KB f32).
// Per strip: stash(i+1) [counted vmcnt wait] -> issue loads(i+2) -> MFMA(i) ->
// scatter -> {lgkmcnt(0); s_barrier} (NO vmcnt drain) -> epilogue stores(i).
// Stores stay in flight across barriers; loads get a full iteration of slack.
__global__ __launch_bounds__(512, 4) void gemm_main_kernel(
    const float* __restrict__ x, const unsigned short* __restrict__ wsT,
    float* __restrict__ out)
{
  __shared__ f32x4 smemv[3584];  // 56 KB: A[3][8K] @0, R[2][16K] @24576
  unsigned char* S8 = (unsigned char*)smemv;
  const int t = threadIdx.x;
  const int lane = t & 63;
  const int w = t >> 6;
  const int p = lane & 15;
  const int hi = lane >> 4;

  // XCD-trio remap (neutral but harmless; keeps channel-trios co-XCD)
  const int bid = blockIdx.x;
  int c, bc;
  if (bid < 504) {
    bc = (bid / 24) * 8 + (bid & 7);
    c = (bid % 24) >> 3;
  } else {
    int idx = bid - 504;
    bc = 168 + idx / 3;
    c = idx % 3;
  }

  // ---- T fragments in registers: 2 mf x 8 ks x 16 B = 64 VGPR
  short8 tA0[8], tA1[8];
  {
    const unsigned short* tp = wsT + (size_t)c * 65536 + (size_t)(w * 32 + p) * 256 + hi * 8;
#pragma unroll
    for (int ks = 0; ks < 8; ++ks) tA0[ks] = *(const short8*)(tp + ks * 32);
    tp += 4096;
#pragma unroll
    for (int ks = 0; ks < 8; ++ks) tA1[ks] = *(const short8*)(tp + ks * 32);
  }

  // ---- staging geometry (strip = 1024 float4, 2/thread; slot1 = slot0 +256B / +4096 fl)
  const int c40 = t & 63;
  const int r0_ = t >> 6;
  const int p0s = c40 >> 2;
  const int lb0 = p0s * 512 + ((r0_ * 32 + (c40 & 3) * 8) ^ ((p0s & 7) << 4));
  const size_t g0 = (size_t)r0_ * 512 + c40 * 4;

  auto src_base = [&](int s) -> const float* {
    int b_ = s >> 6, t6 = s & 63, ph = t6 >> 1, half = t6 & 1;
    return x + (((size_t)(b_ * 3 + c) * 512 + ph * 16) << 9) + half * 256;
  };
  auto stash = [&](unsigned char* Ab, const float4& fa, const float4& fb) {
    unsigned lo = (unsigned)f2bf(fa.x) | ((unsigned)f2bf(fa.y) << 16);
    unsigned hh = (unsigned)f2bf(fa.z) | ((unsigned)f2bf(fa.w) << 16);
    *(uint2*)(Ab + lb0) = make_uint2(lo, hh);
    lo = (unsigned)f2bf(fb.x) | ((unsigned)f2bf(fb.y) << 16);
    hh = (unsigned)f2bf(fb.z) | ((unsigned)f2bf(fb.w) << 16);
    *(uint2*)(Ab + lb0 + 256) = make_uint2(lo, hh);
  };

  const int swz = (p & 7) << 4;
  // epilogue geometry: wave w stores patches w and w+8 (LDS offsets +8192/+4096)
  const int sp0 = w;
  const int rso0 = sp0 * 1024 + ((lane * 16) ^ ((sp0 & 7) << 4));
  const int aso0 = sp0 * 512 + ((lane * 8) ^ ((sp0 & 7) << 4));
  float* recp = out + (size_t)25165824;

  // ---- prologue: strip bc -> A[0]; strip bc+170 -> regs (bc+170 < 2048 always)
  float4 pfa, pfb, qfa, qfb;
  {
    const float* sb = src_base(bc);
    pfa = *(const float4*)(sb + g0);
    pfb = *(const float4*)(sb + g0 + 4096);
  }
  stash(S8, pfa, pfb);
  {
    const float* sb = src_base(bc + 170);
    pfa = *(const float4*)(sb + g0);
    pfb = *(const float4*)(sb + g0 + 4096);
  }
  asm volatile("s_waitcnt lgkmcnt(0)\n\ts_barrier" ::: "memory");

  auto body = [&](int s, int i, float4& cfa, float4& cfb, float4& nfa, float4& nfb) {
    unsigned char* Ac = S8 + (i % 3) * 8192;
    unsigned char* An = S8 + ((i + 1) % 3) * 8192;
    unsigned char* Rc = S8 + 24576 + (i & 1) * 16384;

    // 1: stash strip i+1 (cf loaded a full iteration ago -> counted vmcnt wait,
    //    leaves previous epilogue's stores in flight)
    if (s + 170 < 2048) stash(An, cfa, cfb);
    // 2: issue loads strip i+2 (consumed at next iter's stash)
    if (s + 340 < 2048) {
      const float* sb = src_base(s + 340);
      nfa = *(const float4*)(sb + g0);
      nfb = *(const float4*)(sb + g0 + 4096);
    }
    // 3: MFMA strip i, 4 independent chains
    const unsigned char* bp = Ac + p * 512;
    const f32x4 z = {0.f, 0.f, 0.f, 0.f};
    f32x4 a0a = z, a0b = z, a1a = z, a1b = z;
#pragma unroll
    for (int ks = 0; ks < 4; ++ks) {
      short8 bf = *(const short8*)(bp + ((ks * 64 + hi * 16) ^ swz));
      a0a = __builtin_amdgcn_mfma_f32_16x16x32_bf16(tA0[ks], bf, a0a, 0, 0, 0);
      a1a = __builtin_amdgcn_mfma_f32_16x16x32_bf16(tA1[ks], bf, a1a, 0, 0, 0);
    }
#pragma unroll
    for (int ks = 4; ks < 8; ++ks) {
      short8 bf = *(const short8*)(bp + ((ks * 64 + hi * 16) ^ swz));
      a0b = __builtin_amdgcn_mfma_f32_16x16x32_bf16(tA0[ks], bf, a0b, 0, 0, 0);
      a1b = __builtin_amdgcn_mfma_f32_16x16x32_bf16(tA1[ks], bf, a1b, 0, 0, 0);
    }
    f32x4 acc0 = a0a + a0b;
    f32x4 acc1 = a1a + a1b;

    // 4: scatter acc -> R[i&1], swizzled [patch][outcol]
    {
      int oc0 = w * 32 + hi * 4;
      *(f32x4*)(Rc + p * 1024 + ((oc0 * 4) ^ swz)) = acc0;
      *(f32x4*)(Rc + p * 1024 + (((oc0 + 16) * 4) ^ swz)) = acc1;
    }
    // 5: LDS-only barrier (global loads/stores are wave-private -> no vmcnt drain)
    asm volatile("s_waitcnt lgkmcnt(0)\n\ts_barrier" ::: "memory");
    __builtin_amdgcn_sched_barrier(0);

    // 6: epilogue — wave-contiguous 1 KB/patch stores (stay in flight past barriers)
    {
      int b_ = s >> 6, t6 = s & 63, ph = t6 >> 1, half = t6 & 1;
      size_t nbase = ((size_t)b_ * 1024 + ph * 32 + half * 16);
      size_t pb = ((nbase + sp0) * 3 + c) << 8;
      {
        f32x4 rv = *(const f32x4*)(Rc + rso0);
        uint2 pv = *(const uint2*)(Ac + aso0);
        float q0 = bf2f((unsigned short)(pv.x & 0xFFFF));
        float q1 = bf2f((unsigned short)(pv.x >> 16));
        float q2 = bf2f((unsigned short)(pv.y & 0xFFFF));
        float q3 = bf2f((unsigned short)(pv.y >> 16));
        *(float4*)(out + pb + lane * 4) =
            make_float4(q0 - rv[0], q1 - rv[1], q2 - rv[2], q3 - rv[3]);
        *(float4*)(recp + pb + lane * 4) = make_float4(rv[0], rv[1], rv[2], rv[3]);
      }
      {
        size_t pb1 = pb + 6144;  // patch sp0+8
        f32x4 rv = *(const f32x4*)(Rc + rso0 + 8192);
        uint2 pv = *(const uint2*)(Ac + aso0 + 4096);
        float q0 = bf2f((unsigned short)(pv.x & 0xFFFF));
        float q1 = bf2f((unsigned short)(pv.x >> 16));
        float q2 = bf2f((unsigned short)(pv.y & 0xFFFF));
        float q3 = bf2f((unsigned short)(pv.y >> 16));
        *(float4*)(out + pb1 + lane * 4) =
            make_float4(q0 - rv[0], q1 - rv[1], q2 - rv[2], q3 - rv[3]);
        *(float4*)(recp + pb1 + lane * 4) = make_float4(rv[0], rv[1], rv[2], rv[3]);
      }
    }
  };

  // 2x-unrolled ping-pong (no pf=na register copy -> no early vmcnt wait)
  int s = bc, i = 0;
  for (;;) {
    body(s, i, pfa, pfb, qfa, qfb);
    s += 170; ++i;
    if (s >= 2048) break;
    body(s, i, qfa, qfb, pfa, pfb);
    s += 170; ++i;
    if (s >= 2048) break;
  }
}

extern "C" void kernel_launch(void* const* d_in, const int* in_sizes, int n_in,
                              void* d_out, int out_size, void* d_ws, size_t ws_size,
                              hipStream_t stream) {
  const float* x  = (const float*)d_in[0];
  const float* w1 = (const float*)d_in[1];
  const float* b1 = (const float*)d_in[2];
  const float* w2 = (const float*)d_in[3];
  const float* b2 = (const float*)d_in[4];
  const float* w3 = (const float*)d_in[5];
  const float* b3 = (const float*)d_in[6];
  float* out = (float*)d_out;

  float* ws = (float*)d_ws;
  float* hbar = ws + 768;                             // 64 floats
  unsigned short* wsT = (unsigned short*)(ws + 832);  // 3 x 256 x 256 bf16

  hipMemsetAsync(hbar, 0, 64 * sizeof(float), stream);
  mlp_h2_kernel<<<8, 256, 0, stream>>>(w1, b1, w2, b2, hbar);
  build_TM_kernel<<<6, 1024, 0, stream>>>(hbar, w3, b3, wsT,
                                          out + (size_t)50331648);
  gemm_main_kernel<<<510, 512, 0, stream>>>(x, wsT, out);
}

// Round 6
// 304.476 us; speedup vs baseline: 1.0363x; 1.0363x over previous
//
#include <hip/hip_runtime.h>

typedef __attribute__((ext_vector_type(8))) short short8;
typedef __attribute__((ext_vector_type(4))) float f32x4;

__device__ __forceinline__ unsigned short f2bf(float f) {
  unsigned u = __float_as_uint(f);
  u += 0x7FFF + ((u >> 16) & 1);
  return (unsigned short)(u >> 16);
}
__device__ __forceinline__ float bf2f(unsigned short h) {
  return __uint_as_float(((unsigned)h) << 16);
}

// ---------------- kernel 1: h2 row-sums -> per-block partials (no atomics) ------
// grid 8 x 256. Block bi handles coord rows [bi*32, bi*32+32); writes hbar8[bi][64].
__global__ __launch_bounds__(256) void mlp_h2_kernel(
    const float* __restrict__ w1, const float* __restrict__ b1,
    const float* __restrict__ w2, const float* __restrict__ b2,
    float* __restrict__ hbar8)
{
  __shared__ float W2T[64][65];
  __shared__ float h1s[32][64];
  __shared__ float partial[4][64];
  const int t = threadIdx.x;
  const int k = t & 63, rg = t >> 6;

  for (int v = 0; v < 16; ++v) {
    int idx = v * 256 + t;
    W2T[idx & 63][idx >> 6] = w2[idx];  // W2T[col][row] = W2[row][col]
  }
  const int r0 = blockIdx.x * 32;
  for (int v = 0; v < 8; ++v) {
    int idx = v * 256 + t;
    int rl = idx >> 6, j = idx & 63;
    int r = r0 + rl;
    float gx = (float)(r >> 4) * (1.0f / 15.0f);
    float gy = (float)(r & 15) * (1.0f / 15.0f);
    float h = gx * w1[2 * j] + gy * w1[2 * j + 1] + b1[j];
    h1s[rl][j] = fmaxf(h, 0.0f);
  }
  __syncthreads();

  float acc[8] = {0, 0, 0, 0, 0, 0, 0, 0};
  for (int j = 0; j < 64; ++j) {
    float w = W2T[j][k];
#pragma unroll
    for (int rr = 0; rr < 8; ++rr)
      acc[rr] += h1s[rg * 8 + rr][j] * w;
  }
  float b2v = b2[k];
  float s = 0.0f;
#pragma unroll
  for (int rr = 0; rr < 8; ++rr) s += fmaxf(acc[rr] + b2v, 0.0f);
  partial[rg][k] = s;
  __syncthreads();
  if (t < 64) {
    hbar8[blockIdx.x * 64 + t] =
        partial[0][t] + partial[1][t] + partial[2][t] + partial[3][t];
  }
}

// ---------------- main kernel: per-patch DCT/mask/IDCT via MFMA ----------------
// One wave = 8 horizontally-adjacent patches of one (b, c, ph).
// grid 3072 x 256  (12288 waves = 32b * 3c * 32ph * 4 pw-groups)
// Mf is computed per-block from hbar8 (folded mlp_out); blocks {0,32,64} write it.
__global__ __launch_bounds__(256) void dct_main_kernel(
    const float* __restrict__ x,
    const float* __restrict__ hbar8,
    const float* __restrict__ w3,
    const float* __restrict__ b3,
    float* __restrict__ out)
{
  __shared__ uint4 lds_buf[4][400];  // per wave: 8 patches x 800 B (bf16, row stride 48 B)
  __shared__ float MfL[256];
  __shared__ float hbL[64];
  const int t = threadIdx.x;
  const int lane = t & 63;
  const int wib = t >> 6;
  unsigned char* my = (unsigned char*)lds_buf[wib];

  // ---- folded mlp_out: hbar reduce + this block's channel Mf row ----
  if (t < 64) {
    float s = 0.f;
#pragma unroll
    for (int bi = 0; bi < 8; ++bi) s += hbar8[bi * 64 + t];
    hbL[t] = s;
  }
  __syncthreads();

  const int bidx = blockIdx.x;
  const int cblk = (bidx >> 5) % 3;
  {
    int j = cblk * 256 + t;
    const float* w3r = w3 + (size_t)j * 64;
    float s = 0.f;
    for (int kk = 0; kk < 64; ++kk) s += hbL[kk] * w3r[kk];
    float o = b3[j] + s * (1.0f / 256.0f);
    float m = 1.0f / (1.0f + expf(-o));
    MfL[t] = m;
    if (bidx == cblk * 32)  // b==0, ph==0 block of this channel
      out[(size_t)50331648 + j] = m;
  }

  int wave_id = bidx * 4 + wib;
  const int pwg = wave_id & 3;
  int tt = wave_id >> 2;
  const int ph = tt & 31;
  tt >>= 5;
  const int c = tt % 3;
  const int b = tt / 3;

  const int n = lane & 15;
  const int g = lane >> 4;

  size_t xbase = (((size_t)(b * 3 + c) * 512) + (size_t)ph * 16) * 512 + (size_t)pwg * 128;

  // ---- stage 16 rows x 128 cols (fp32 -> bf16) to LDS: patch p row j at p*800 + j*48
  {
    const float* srcf = x + xbase;
    const int r2 = lane >> 5;   // row within pair
    const int cc = lane & 31;   // 4-float chunk within the 128-col row
    const int p = cc >> 2, c4 = cc & 3;
#pragma unroll
    for (int v = 0; v < 8; ++v) {
      float4 f = *(const float4*)(srcf + (size_t)(2 * v + r2) * 512 + cc * 4);
      unsigned lo = (unsigned)f2bf(f.x) | ((unsigned)f2bf(f.y) << 16);
      unsigned hi = (unsigned)f2bf(f.z) | ((unsigned)f2bf(f.w) << 16);
      *(uint2*)(my + p * 800 + (2 * v + r2) * 48 + c4 * 8) = make_uint2(lo, hi);
    }
  }

  // ---- D operands (bf16). D[i][k] = s(i)*cos(pi*(2i+1)k/32), s(0)=0.25 else sqrt(2)/4
  short8 B1, B2, B3;
  {
    const float PIc = 3.14159265358979323846f;
    const float SC = 0.35355339059327373f;
#pragma unroll
    for (int j = 0; j < 8; ++j) {
      int kk = 8 * g + j;
      float v = 0.0f;
      if (kk < 16) {  // B1[k][n] = D^T[k][n] = D[n][k]; K-rows 16..31 zero
        float sc = (n == 0) ? 0.25f : SC;
        v = sc * cosf(PIc * (float)((2 * n + 1) * kk) * (1.0f / 32.0f));
      }
      B1[j] = (short)f2bf(v);
    }
#pragma unroll
    for (int j = 0; j < 4; ++j) {  // row-interleaved for the C-as-A transpose trick
      int r = 4 * g + j;
      float sc_n = (n == 0) ? 0.25f : SC;
      B2[j] = (short)f2bf(sc_n * cosf(PIc * (float)((2 * n + 1) * r) * (1.0f / 32.0f)));  // D^T[r][n]
      float sc_r = (r == 0) ? 0.25f : SC;
      B3[j] = (short)f2bf(sc_r * cosf(PIc * (float)((2 * r + 1) * n) * (1.0f / 32.0f)));  // D[r][n]
      B2[j + 4] = 0;
      B3[j + 4] = 0;
    }
  }

  __syncthreads();

  // ---- mask values (fp32) for this lane's (row=n, cols 4g..4g+3), channel c
  f32x4 Mv;
  {
    const int mb = n * 16 + 4 * g;
    Mv[0] = MfL[mb]; Mv[1] = MfL[mb + 1]; Mv[2] = MfL[mb + 2]; Mv[3] = MfL[mb + 3];
  }

  const f32x4 zero4 = {0.f, 0.f, 0.f, 0.f};
  size_t obase0 = ((((size_t)b * 1024 + (size_t)ph * 32 + pwg * 8) * 3) + c) * 256 + n * 16 + 4 * g;
  float* resp = out;
  float* recp = out + (size_t)25165824;

  for (int p = 0; p < 8; ++p) {
    const unsigned char* pb = my + p * 800;

    // S1 = P * D^T
    short8 A1 = {0, 0, 0, 0, 0, 0, 0, 0};
    if (lane < 32) {
      uint4 t4 = *(const uint4*)(pb + n * 48 + g * 16);
      A1 = __builtin_bit_cast(short8, t4);
    }
    f32x4 s1 = __builtin_amdgcn_mfma_f32_16x16x32_bf16(A1, B1, zero4, 0, 0, 0);

    // S2 = S1^T * D^T = Dcoeff^T  (C-regs fed back as A == transpose)
    short8 A2 = {(short)f2bf(s1[0]), (short)f2bf(s1[1]), (short)f2bf(s1[2]), (short)f2bf(s1[3]), 0, 0, 0, 0};
    f32x4 s2 = __builtin_amdgcn_mfma_f32_16x16x32_bf16(A2, B2, zero4, 0, 0, 0);

    // mask (fp32), then S3 = Dmasked * D
    short8 A3 = {(short)f2bf(s2[0] * Mv[0]), (short)f2bf(s2[1] * Mv[1]),
                 (short)f2bf(s2[2] * Mv[2]), (short)f2bf(s2[3] * Mv[3]), 0, 0, 0, 0};
    f32x4 s3 = __builtin_amdgcn_mfma_f32_16x16x32_bf16(A3, B3, zero4, 0, 0, 0);

    // S4 = S3^T * D = recon^T : lane holds recon[n][4g+q], q=0..3 (row-adjacent)
    short8 A4 = {(short)f2bf(s3[0]), (short)f2bf(s3[1]), (short)f2bf(s3[2]), (short)f2bf(s3[3]), 0, 0, 0, 0};
    f32x4 s4 = __builtin_amdgcn_mfma_f32_16x16x32_bf16(A4, B3, zero4, 0, 0, 0);

    // residual = P - recon  (P[n][4g..4g+3] is one 8B LDS read)
    uint2 pv = *(const uint2*)(pb + n * 48 + 8 * g);
    float p0 = bf2f((unsigned short)(pv.x & 0xFFFF));
    float p1 = bf2f((unsigned short)(pv.x >> 16));
    float p2 = bf2f((unsigned short)(pv.y & 0xFFFF));
    float p3 = bf2f((unsigned short)(pv.y >> 16));

    size_t ob = obase0 + (size_t)p * 768;  // next patch: +3*256 elems
    float4 rv = make_float4(p0 - s4[0], p1 - s4[1], p2 - s4[2], p3 - s4[3]);
    float4 cv = make_float4(s4[0], s4[1], s4[2], s4[3]);
    *(float4*)(resp + ob) = rv;   // fp32 outputs, 16 B/lane, fully coalesced per patch
    *(float4*)(recp + ob) = cv;
  }
}

extern "C" void kernel_launch(void* const* d_in, const int* in_sizes, int n_in,
                              void* d_out, int out_size, void* d_ws, size_t ws_size,
                              hipStream_t stream) {
  const float* x  = (const float*)d_in[0];
  const float* w1 = (const float*)d_in[1];
  const float* b1 = (const float*)d_in[2];
  const float* w2 = (const float*)d_in[3];
  const float* b2 = (const float*)d_in[4];
  const float* w3 = (const float*)d_in[5];
  const float* b3 = (const float*)d_in[6];
  float* out = (float*)d_out;

  float* hbar8 = (float*)d_ws;  // 8 x 64 partial sums

  mlp_h2_kernel<<<8, 256, 0, stream>>>(w1, b1, w2, b2, hbar8);
  dct_main_kernel<<<3072, 256, 0, stream>>>(x, hbar8, w3, b3, out);
}

// Round 7
// 295.725 us; speedup vs baseline: 1.0669x; 1.0296x over previous
//
#include <hip/hip_runtime.h>

typedef __attribute__((ext_vector_type(8))) short short8;
typedef __attribute__((ext_vector_type(4))) float f32x4;

__device__ __forceinline__ unsigned short f2bf(float f) {
  unsigned u = __float_as_uint(f);
  u += 0x7FFF + ((u >> 16) & 1);
  return (unsigned short)(u >> 16);
}
__device__ __forceinline__ float bf2f(unsigned short h) {
  return __uint_as_float(((unsigned)h) << 16);
}

// ---------------- kernel 1: h2 row-sums -> per-block partials (no atomics) ------
// grid 8 x 256. Block bi handles coord rows [bi*32, bi*32+32); writes hbar8[bi][64].
__global__ __launch_bounds__(256) void mlp_h2_kernel(
    const float* __restrict__ w1, const float* __restrict__ b1,
    const float* __restrict__ w2, const float* __restrict__ b2,
    float* __restrict__ hbar8)
{
  __shared__ float W2T[64][65];
  __shared__ float h1s[32][64];
  __shared__ float partial[4][64];
  const int t = threadIdx.x;
  const int k = t & 63, rg = t >> 6;

  for (int v = 0; v < 16; ++v) {
    int idx = v * 256 + t;
    W2T[idx & 63][idx >> 6] = w2[idx];  // W2T[col][row] = W2[row][col]
  }
  const int r0 = blockIdx.x * 32;
  for (int v = 0; v < 8; ++v) {
    int idx = v * 256 + t;
    int rl = idx >> 6, j = idx & 63;
    int r = r0 + rl;
    float gx = (float)(r >> 4) * (1.0f / 15.0f);
    float gy = (float)(r & 15) * (1.0f / 15.0f);
    float h = gx * w1[2 * j] + gy * w1[2 * j + 1] + b1[j];
    h1s[rl][j] = fmaxf(h, 0.0f);
  }
  __syncthreads();

  float acc[8] = {0, 0, 0, 0, 0, 0, 0, 0};
  for (int j = 0; j < 64; ++j) {
    float w = W2T[j][k];
#pragma unroll
    for (int rr = 0; rr < 8; ++rr)
      acc[rr] += h1s[rg * 8 + rr][j] * w;
  }
  float b2v = b2[k];
  float s = 0.0f;
#pragma unroll
  for (int rr = 0; rr < 8; ++rr) s += fmaxf(acc[rr] + b2v, 0.0f);
  partial[rg][k] = s;
  __syncthreads();
  if (t < 64) {
    hbar8[blockIdx.x * 64 + t] =
        partial[0][t] + partial[1][t] + partial[2][t] + partial[3][t];
  }
}

// ---------------- kernel 2: layer 3 + mean + sigmoid (reduces hbar8) ----------
// grid 3 x 256 -> j = 0..767.  Mf[j] = sigmoid(b3[j] + (hbar/256) . W3[j])
__global__ __launch_bounds__(256) void mlp_out_kernel(
    const float* __restrict__ hbar8, const float* __restrict__ w3,
    const float* __restrict__ b3, float* __restrict__ wsM,
    float* __restrict__ outMf)
{
  __shared__ float hbL[64];
  const int t = threadIdx.x;
  if (t < 64) {
    float s = 0.f;
#pragma unroll
    for (int bi = 0; bi < 8; ++bi) s += hbar8[bi * 64 + t];
    hbL[t] = s;
  }
  __syncthreads();
  int j = blockIdx.x * 256 + t;  // 0..767
  const float* w3r = w3 + (size_t)j * 64;
  float s = 0.0f;
  for (int kk = 0; kk < 64; ++kk)
    s += hbL[kk] * w3r[kk];
  float o = b3[j] + s * (1.0f / 256.0f);
  float m = 1.0f / (1.0f + expf(-o));
  wsM[j] = m;
  outMf[j] = m;  // fp32 output
}

// ---------------- main kernel: per-patch DCT/mask/IDCT via MFMA ----------------
// One wave = 8 horizontally-adjacent patches of one (b, c, ph).
// grid 3072 x 256  (12288 waves = 32b * 3c * 32ph * 4 pw-groups)
// (proven fastest main kernel — baseline 297.1 µs configuration, verbatim)
__global__ __launch_bounds__(256) void dct_main_kernel(
    const float* __restrict__ x,
    const float* __restrict__ wsM,
    float* __restrict__ out)
{
  __shared__ uint4 lds_buf[4][400];  // per wave: 8 patches x 800 B (bf16, row stride 48 B)
  const int lane = threadIdx.x & 63;
  const int wib = threadIdx.x >> 6;
  unsigned char* my = (unsigned char*)lds_buf[wib];

  int wave_id = blockIdx.x * 4 + wib;
  const int pwg = wave_id & 3;
  int tt = wave_id >> 2;
  const int ph = tt & 31;
  tt >>= 5;
  const int c = tt % 3;
  const int b = tt / 3;

  const int n = lane & 15;
  const int g = lane >> 4;

  size_t xbase = (((size_t)(b * 3 + c) * 512) + (size_t)ph * 16) * 512 + (size_t)pwg * 128;

  // ---- stage 16 rows x 128 cols (fp32 -> bf16) to LDS: patch p row j at p*800 + j*48
  {
    const float* srcf = x + xbase;
    const int r2 = lane >> 5;   // row within pair
    const int cc = lane & 31;   // 4-float chunk within the 128-col row
    const int p = cc >> 2, c4 = cc & 3;
#pragma unroll
    for (int v = 0; v < 8; ++v) {
      float4 f = *(const float4*)(srcf + (size_t)(2 * v + r2) * 512 + cc * 4);
      unsigned lo = (unsigned)f2bf(f.x) | ((unsigned)f2bf(f.y) << 16);
      unsigned hi = (unsigned)f2bf(f.z) | ((unsigned)f2bf(f.w) << 16);
      *(uint2*)(my + p * 800 + (2 * v + r2) * 48 + c4 * 8) = make_uint2(lo, hi);
    }
  }

  // ---- mask values (fp32) for this lane's (row=n, cols 4g..4g+3), channel c
  f32x4 Mv;
  {
    const float* mp = wsM + c * 256 + n * 16 + 4 * g;
    Mv[0] = mp[0]; Mv[1] = mp[1]; Mv[2] = mp[2]; Mv[3] = mp[3];
  }

  // ---- D operands (bf16). D[i][k] = s(i)*cos(pi*(2i+1)k/32), s(0)=0.25 else sqrt(2)/4
  short8 B1, B2, B3;
  {
    const float PIc = 3.14159265358979323846f;
    const float SC = 0.35355339059327373f;
#pragma unroll
    for (int j = 0; j < 8; ++j) {
      int kk = 8 * g + j;
      float v = 0.0f;
      if (kk < 16) {  // B1[k][n] = D^T[k][n] = D[n][k]; K-rows 16..31 zero
        float sc = (n == 0) ? 0.25f : SC;
        v = sc * cosf(PIc * (float)((2 * n + 1) * kk) * (1.0f / 32.0f));
      }
      B1[j] = (short)f2bf(v);
    }
#pragma unroll
    for (int j = 0; j < 4; ++j) {  // row-interleaved for the C-as-A transpose trick
      int r = 4 * g + j;
      float sc_n = (n == 0) ? 0.25f : SC;
      B2[j] = (short)f2bf(sc_n * cosf(PIc * (float)((2 * n + 1) * r) * (1.0f / 32.0f)));  // D^T[r][n]
      float sc_r = (r == 0) ? 0.25f : SC;
      B3[j] = (short)f2bf(sc_r * cosf(PIc * (float)((2 * r + 1) * n) * (1.0f / 32.0f)));  // D[r][n]
      B2[j + 4] = 0;
      B3[j + 4] = 0;
    }
  }

  __syncthreads();

  const f32x4 zero4 = {0.f, 0.f, 0.f, 0.f};
  size_t obase0 = ((((size_t)b * 1024 + (size_t)ph * 32 + pwg * 8) * 3) + c) * 256 + n * 16 + 4 * g;
  float* resp = out;
  float* recp = out + (size_t)25165824;

  for (int p = 0; p < 8; ++p) {
    const unsigned char* pb = my + p * 800;

    // S1 = P * D^T
    short8 A1 = {0, 0, 0, 0, 0, 0, 0, 0};
    if (lane < 32) {
      uint4 t4 = *(const uint4*)(pb + n * 48 + g * 16);
      A1 = __builtin_bit_cast(short8, t4);
    }
    f32x4 s1 = __builtin_amdgcn_mfma_f32_16x16x32_bf16(A1, B1, zero4, 0, 0, 0);

    // S2 = S1^T * D^T = Dcoeff^T  (C-regs fed back as A == transpose)
    short8 A2 = {(short)f2bf(s1[0]), (short)f2bf(s1[1]), (short)f2bf(s1[2]), (short)f2bf(s1[3]), 0, 0, 0, 0};
    f32x4 s2 = __builtin_amdgcn_mfma_f32_16x16x32_bf16(A2, B2, zero4, 0, 0, 0);

    // mask (fp32), then S3 = Dmasked * D
    short8 A3 = {(short)f2bf(s2[0] * Mv[0]), (short)f2bf(s2[1] * Mv[1]),
                 (short)f2bf(s2[2] * Mv[2]), (short)f2bf(s2[3] * Mv[3]), 0, 0, 0, 0};
    f32x4 s3 = __builtin_amdgcn_mfma_f32_16x16x32_bf16(A3, B3, zero4, 0, 0, 0);

    // S4 = S3^T * D = recon^T : lane holds recon[n][4g+q], q=0..3 (row-adjacent)
    short8 A4 = {(short)f2bf(s3[0]), (short)f2bf(s3[1]), (short)f2bf(s3[2]), (short)f2bf(s3[3]), 0, 0, 0, 0};
    f32x4 s4 = __builtin_amdgcn_mfma_f32_16x16x32_bf16(A4, B3, zero4, 0, 0, 0);

    // residual = P - recon  (P[n][4g..4g+3] is one 8B LDS read)
    uint2 pv = *(const uint2*)(pb + n * 48 + 8 * g);
    float p0 = bf2f((unsigned short)(pv.x & 0xFFFF));
    float p1 = bf2f((unsigned short)(pv.x >> 16));
    float p2 = bf2f((unsigned short)(pv.y & 0xFFFF));
    float p3 = bf2f((unsigned short)(pv.y >> 16));

    size_t ob = obase0 + (size_t)p * 768;  // next patch: +3*256 elems
    float4 rv = make_float4(p0 - s4[0], p1 - s4[1], p2 - s4[2], p3 - s4[3]);
    float4 cv = make_float4(s4[0], s4[1], s4[2], s4[3]);
    *(float4*)(resp + ob) = rv;   // fp32 outputs, 16 B/lane, fully coalesced per patch
    *(float4*)(recp + ob) = cv;
  }
}

extern "C" void kernel_launch(void* const* d_in, const int* in_sizes, int n_in,
                              void* d_out, int out_size, void* d_ws, size_t ws_size,
                              hipStream_t stream) {
  const float* x  = (const float*)d_in[0];
  const float* w1 = (const float*)d_in[1];
  const float* b1 = (const float*)d_in[2];
  const float* w2 = (const float*)d_in[3];
  const float* b2 = (const float*)d_in[4];
  const float* w3 = (const float*)d_in[5];
  const float* b3 = (const float*)d_in[6];
  float* out = (float*)d_out;

  float* ws = (float*)d_ws;
  float* hbar8 = ws;           // 8 x 64 partial sums
  float* wsM = ws + 512;       // 768 floats: Mf fp32

  mlp_h2_kernel<<<8, 256, 0, stream>>>(w1, b1, w2, b2, hbar8);
  mlp_out_kernel<<<3, 256, 0, stream>>>(hbar8, w3, b3, wsM, out + (size_t)50331648);
  dct_main_kernel<<<3072, 256, 0, stream>>>(x, wsM, out);
}